// Round 1
// baseline (2354.066 us; speedup 1.0000x reference)
//
#include <hip/hip_runtime.h>
#include <hip/hip_bf16.h>
#include <math.h>

#define B_ 8
#define N_ 625
#define D_ 128
#define H_ 8
#define HD_ 16
#define MLP_ 4096
#define SCALE_ 0.25f
#define M_ (B_ * N_)   // 5000 rows

// ---------------- wave-wide reductions (wave64) ----------------
__device__ __forceinline__ float wave_reduce_sum(float v) {
#pragma unroll
    for (int off = 32; off > 0; off >>= 1) v += __shfl_xor(v, off, 64);
    return v;
}
__device__ __forceinline__ float wave_reduce_max(float v) {
#pragma unroll
    for (int off = 32; off > 0; off >>= 1) v = fmaxf(v, __shfl_xor(v, off, 64));
    return v;
}

// ---------------- LayerNorm: one wave per row (D=128, 2 elems/lane) ----------------
__global__ void ln_kernel(const float* __restrict__ x, const float* __restrict__ g,
                          const float* __restrict__ b, float* __restrict__ out) {
    int wid = threadIdx.x >> 6;
    int lid = threadIdx.x & 63;
    int row = blockIdx.x * 4 + wid;
    if (row >= M_) return;
    const float* xr = x + (size_t)row * D_;
    float x0 = xr[lid], x1 = xr[lid + 64];
    float mu = wave_reduce_sum(x0 + x1) * (1.0f / D_);
    float d0 = x0 - mu, d1 = x1 - mu;
    float var = wave_reduce_sum(d0 * d0 + d1 * d1) * (1.0f / D_);
    float inv = rsqrtf(var + 1e-5f);
    float* orow = out + (size_t)row * D_;
    orow[lid]      = d0 * inv * g[lid] + b[lid];
    orow[lid + 64] = d1 * inv * g[lid + 64] + b[lid + 64];
}

// ---------------- generic fp32 GEMM: C = A(MxK) @ B(KxN) [+bias] [+resid] ----------------
// 64x64 tile, 256 threads, 4x4 microtile, K staged 16 at a time in LDS.
template <bool BIAS, bool RESID>
__global__ void gemm64(const float* __restrict__ A, const float* __restrict__ Bm,
                       const float* __restrict__ bias, const float* __restrict__ resid,
                       float* __restrict__ C, int M, int Nc, int K) {
    __shared__ float As[16][65];
    __shared__ float Bs[16][65];
    int tid = threadIdx.x;
    int tx = tid & 15, ty = tid >> 4;
    int bN = blockIdx.x * 64, bM = blockIdx.y * 64;
    float acc[4][4] = {};
    for (int k0 = 0; k0 < K; k0 += 16) {
        __syncthreads();
#pragma unroll
        for (int i = 0; i < 4; i++) {
            int e = tid + i * 256;
            int m = e >> 4, kk = e & 15;
            int gm = bM + m;
            As[kk][m] = (gm < M) ? A[(size_t)gm * K + k0 + kk] : 0.0f;
        }
#pragma unroll
        for (int i = 0; i < 4; i++) {
            int e = tid + i * 256;
            int kk = e >> 6, n = e & 63;
            int gn = bN + n;
            Bs[kk][n] = (gn < Nc) ? Bm[(size_t)(k0 + kk) * Nc + gn] : 0.0f;
        }
        __syncthreads();
#pragma unroll
        for (int kk = 0; kk < 16; kk++) {
            float a[4], bv[4];
#pragma unroll
            for (int i = 0; i < 4; i++) a[i] = As[kk][ty + i * 16];
#pragma unroll
            for (int j = 0; j < 4; j++) bv[j] = Bs[kk][tx + j * 16];
#pragma unroll
            for (int i = 0; i < 4; i++)
#pragma unroll
                for (int j = 0; j < 4; j++) acc[i][j] += a[i] * bv[j];
        }
    }
#pragma unroll
    for (int i = 0; i < 4; i++) {
        int gm = bM + ty + i * 16;
        if (gm >= M) continue;
#pragma unroll
        for (int j = 0; j < 4; j++) {
            int gn = bN + tx + j * 16;
            if (gn >= Nc) continue;
            float v = acc[i][j];
            if (BIAS) v += bias[gn];
            if (RESID) v += resid[(size_t)gm * Nc + gn];
            C[(size_t)gm * Nc + gn] = v;
        }
    }
}

// ---------------- masked attention: one wave per (b,h,row) ----------------
// qkv layout per row: [3][H][hd] (col = which*128 + h*16 + d). Scores kept in
// 10 regs/lane (ceil(625/64)); mask -> max -> exp -> sum -> PV, all in-wave.
__global__ void attn_kernel(const float* __restrict__ qkv, const int* __restrict__ mask,
                            float* __restrict__ o) {
    int wid = threadIdx.x >> 6, lid = threadIdx.x & 63;
    int idx = blockIdx.x * 4 + wid;
    if (idx >= B_ * H_ * N_) return;
    int b = idx / (H_ * N_);
    int rem = idx - b * (H_ * N_);
    int h = rem / N_;
    int r = rem - h * N_;

    const float* base = qkv + (size_t)b * N_ * 384;
    const float* qp = base + (size_t)r * 384 + h * HD_;
    float q[16];
#pragma unroll
    for (int d = 0; d < 16; d++) q[d] = qp[d];

    int m0 = mask[b * 4 + 0], m1 = mask[b * 4 + 1], m2 = mask[b * 4 + 2], m3 = mask[b * 4 + 3];

    const float* kb = base + 128 + h * HD_;
    float s[10];
#pragma unroll
    for (int i = 0; i < 10; i++) {
        int c = lid + i * 64;
        float sv = -INFINITY;
        if (c < N_) {
            int mm = (c < 125) ? m0 : (c < 250) ? m1 : (c < 375) ? m2 : m3;
            bool allow = (c >= 500) || (mm != 0);
            if (allow) {
                const float* kp = kb + (size_t)c * 384;
                float acc = 0.0f;
#pragma unroll
                for (int d = 0; d < 16; d++) acc += q[d] * kp[d];
                sv = acc * SCALE_;
            }
        }
        s[i] = sv;
    }
    float mx = s[0];
#pragma unroll
    for (int i = 1; i < 10; i++) mx = fmaxf(mx, s[i]);
    mx = wave_reduce_max(mx);
    float lsum = 0.0f;
#pragma unroll
    for (int i = 0; i < 10; i++) {
        s[i] = expf(s[i] - mx);   // exp(-inf) = 0 for masked/oob cols
        lsum += s[i];
    }
    lsum = wave_reduce_sum(lsum);
    float inv = 1.0f / lsum;

    float acc[16] = {};
    const float* vb = base + 256 + h * HD_;
#pragma unroll
    for (int i = 0; i < 10; i++) {
        int c = lid + i * 64;
        if (c < N_) {
            const float* vp = vb + (size_t)c * 384;
#pragma unroll
            for (int d = 0; d < 16; d++) acc[d] += s[i] * vp[d];
        }
    }
#pragma unroll
    for (int d = 0; d < 16; d++) acc[d] = wave_reduce_sum(acc[d]);
    float outv = 0.0f;
#pragma unroll
    for (int d = 0; d < 16; d++) outv = (lid == d) ? acc[d] : outv;
    if (lid < 16)
        o[(size_t)(b * N_ + r) * D_ + h * HD_ + lid] = outv * inv;
}

// ---------------- out = resid + b2 (pre-init for MLP atomic accumulation) ----------------
__global__ void init_out(const float* __restrict__ resid, const float* __restrict__ b2,
                         float* __restrict__ dest) {
    int idx = blockIdx.x * 256 + threadIdx.x;
    if (idx < M_ * D_) dest[idx] = resid[idx] + b2[idx & 127];
}

// ---------------- fused MLP: dest += gelu(H2 @ W1 + b1) @ W2, split-K over MLP dim ----------------
// 32-row tile, each block handles 1024 of the 4096 hidden dims (grid.y = 4), atomicAdd out.
__global__ void mlp_kernel(const float* __restrict__ H2, const float* __restrict__ W1,
                           const float* __restrict__ b1f, const float* __restrict__ W2,
                           float* __restrict__ dest) {
    __shared__ float Hs[32][132];
    __shared__ float W1s[16][132];   // transposed: [jj][kk]
    __shared__ float W2s[16][132];
    __shared__ float Ps[32][20];
    int tid = threadIdx.x;
    int rowBase = blockIdx.x * 32;
    int jBase = blockIdx.y * 1024;

#pragma unroll
    for (int i = 0; i < 16; i++) {
        int e = tid + i * 256;
        int r = e >> 7, kk = e & 127;
        int gr = rowBase + r;
        Hs[r][kk] = (gr < M_) ? H2[(size_t)gr * D_ + kk] : 0.0f;
    }
    float acc[4][4] = {};
    int tr = tid >> 5, tc = tid & 31;

    for (int j = 0; j < 1024; j += 16) {
        __syncthreads();
#pragma unroll
        for (int i = 0; i < 8; i++) {
            int e = tid + i * 256;
            int kk = e >> 4, jj = e & 15;
            W1s[jj][kk] = W1[(size_t)kk * MLP_ + jBase + j + jj];
        }
#pragma unroll
        for (int i = 0; i < 8; i++) {
            int e = tid + i * 256;
            int jj = e >> 7, c = e & 127;
            W2s[jj][c] = W2[(size_t)(jBase + j + jj) * D_ + c];
        }
        __syncthreads();
        // P = gelu(Hs @ W1s^T + b1) : 512 elems, 2 per thread, float4 over K
#pragma unroll
        for (int e = tid; e < 512; e += 256) {
            int r = e >> 4, jj = e & 15;
            float sacc = 0.0f;
            const float4* hp = (const float4*)(&Hs[r][0]);
            const float4* wp = (const float4*)(&W1s[jj][0]);
#pragma unroll
            for (int kk = 0; kk < 32; kk++) {
                float4 hv = hp[kk], wv = wp[kk];
                sacc += hv.x * wv.x + hv.y * wv.y + hv.z * wv.z + hv.w * wv.w;
            }
            float sv = sacc + b1f[jBase + j + jj];
            Ps[r][jj] = 0.5f * sv * (1.0f + erff(sv * 0.70710678118f));  // exact gelu
        }
        __syncthreads();
        // acc += Ps(32x16) @ W2s(16x128)
#pragma unroll
        for (int jj = 0; jj < 16; jj++) {
            float w[4], p[4];
#pragma unroll
            for (int jn = 0; jn < 4; jn++) w[jn] = W2s[jj][tc + jn * 32];
#pragma unroll
            for (int in = 0; in < 4; in++) p[in] = Ps[tr + in * 8][jj];
#pragma unroll
            for (int in = 0; in < 4; in++)
#pragma unroll
                for (int jn = 0; jn < 4; jn++) acc[in][jn] += p[in] * w[jn];
        }
    }
#pragma unroll
    for (int in = 0; in < 4; in++) {
        int gr = rowBase + tr + in * 8;
        if (gr >= M_) continue;
#pragma unroll
        for (int jn = 0; jn < 4; jn++)
            atomicAdd(&dest[(size_t)gr * D_ + tc + jn * 32], acc[in][jn]);
    }
}

extern "C" void kernel_launch(void* const* d_in, const int* in_sizes, int n_in,
                              void* d_out, int out_size, void* d_ws, size_t ws_size,
                              hipStream_t stream) {
    const float* x     = (const float*)d_in[0];
    const int*   mask  = (const int*)d_in[1];
    const float* Wqkv  = (const float*)d_in[2];
    const float* Wproj = (const float*)d_in[3];
    const float* bproj = (const float*)d_in[4];
    const float* g1    = (const float*)d_in[5];
    const float* b1    = (const float*)d_in[6];
    const float* g2    = (const float*)d_in[7];
    const float* b2    = (const float*)d_in[8];
    const float* W1f   = (const float*)d_in[9];
    const float* b1f   = (const float*)d_in[10];
    const float* W2f   = (const float*)d_in[11];
    const float* b2f   = (const float*)d_in[12];
    float* out = (float*)d_out;
    float* ws = (float*)d_ws;

    float* xbuf   = ws;                 // 640000 f
    float* hbuf   = ws + 640000;        // 640000 f
    float* qkvbuf = ws + 1280000;       // 1920000 f
    float* obuf   = ws + 3200000;       // 640000 f  (total 15.36 MB)

    for (int l = 0; l < 3; l++) {
        const float* xcur = (l == 0) ? x : xbuf;
        // LN1
        ln_kernel<<<1250, 256, 0, stream>>>(xcur, g1 + l * D_, b1 + l * D_, hbuf);
        // QKV: (5000x128)@(128x384)
        gemm64<false, false><<<dim3(6, 79), 256, 0, stream>>>(
            hbuf, Wqkv + (size_t)l * D_ * 384, nullptr, nullptr, qkvbuf, M_, 384, D_);
        // attention
        attn_kernel<<<10000, 256, 0, stream>>>(qkvbuf, mask, obuf);
        // proj + bias + residual -> xbuf
        gemm64<true, true><<<dim3(2, 79), 256, 0, stream>>>(
            obuf, Wproj + (size_t)l * D_ * D_, bproj + l * D_, xcur, xbuf, M_, D_, D_);
        // LN2
        ln_kernel<<<1250, 256, 0, stream>>>(xbuf, g2 + l * D_, b2 + l * D_, hbuf);
        // MLP (fused, split-K atomics): dest = xbuf + b2f, then += gelu(h@W1+b1)@W2
        float* dest = (l == 2) ? out : xbuf;
        init_out<<<2500, 256, 0, stream>>>(xbuf, b2f + l * D_, dest);
        mlp_kernel<<<dim3(157, 4), 256, 0, stream>>>(
            hbuf, W1f + (size_t)l * D_ * MLP_, b1f + (size_t)l * MLP_,
            W2f + (size_t)l * MLP_ * D_, dest);
    }
}

// Round 2
// 1340.301 us; speedup vs baseline: 1.7564x; 1.7564x over previous
//
#include <hip/hip_runtime.h>
#include <hip/hip_bf16.h>
#include <math.h>

#define B_ 8
#define N_ 625
#define D_ 128
#define H_ 8
#define HD_ 16
#define MLP_ 4096
#define SCALE_ 0.25f
#define M_ 5000

typedef __attribute__((ext_vector_type(8))) short short8;
typedef __attribute__((ext_vector_type(4))) short short4v;
typedef __attribute__((ext_vector_type(4))) float f32x4;

// ---- bf16 split helpers (RNE via bit trick; inputs finite) ----
__device__ __forceinline__ unsigned short f2bf(float f) {
    unsigned u = __float_as_uint(f);
    unsigned r = (u + 0x7FFFu + ((u >> 16) & 1u)) >> 16;
    return (unsigned short)r;
}
__device__ __forceinline__ float bf2f(unsigned short h) {
    return __uint_as_float(((unsigned)h) << 16);
}

// ---- swizzled LDS byte offsets (row-major bf16 tiles) ----
__device__ __forceinline__ int swz256(int row, int kbyte) {  // 128-k rows (256B)
    return row * 256 + (kbyte ^ ((row & 7) << 4));
}
__device__ __forceinline__ int swz64(int row, int kbyte) {   // 32-k rows (64B)
    return row * 64 + (kbyte ^ ((row & 3) << 4));
}

__device__ __forceinline__ float wave_reduce_sum(float v) {
#pragma unroll
    for (int off = 32; off > 0; off >>= 1) v += __shfl_xor(v, off, 64);
    return v;
}
__device__ __forceinline__ float wave_reduce_max(float v) {
#pragma unroll
    for (int off = 32; off > 0; off >>= 1) v = fmaxf(v, __shfl_xor(v, off, 64));
    return v;
}

// ---------------- LayerNorm: one wave per row ----------------
__global__ void ln_kernel(const float* __restrict__ x, const float* __restrict__ g,
                          const float* __restrict__ b, float* __restrict__ out) {
    int wid = threadIdx.x >> 6;
    int lid = threadIdx.x & 63;
    int row = blockIdx.x * 4 + wid;
    if (row >= M_) return;
    const float* xr = x + (size_t)row * D_;
    float x0 = xr[lid], x1 = xr[lid + 64];
    float mu = wave_reduce_sum(x0 + x1) * (1.0f / D_);
    float d0 = x0 - mu, d1 = x1 - mu;
    float var = wave_reduce_sum(d0 * d0 + d1 * d1) * (1.0f / D_);
    float inv = rsqrtf(var + 1e-5f);
    float* orow = out + (size_t)row * D_;
    orow[lid]      = d0 * inv * g[lid] + b[lid];
    orow[lid + 64] = d1 * inv * g[lid + 64] + b[lid + 64];
}

// ---------------- weight transpose + bf16 hi/lo split ----------------
// W [K][N] fp32 -> Th/Tl [N][K] bf16 (per blockIdx.z layer)
__global__ void tsplit(const float* __restrict__ W, unsigned short* __restrict__ Th,
                       unsigned short* __restrict__ Tl, int K, int N) {
    size_t zo = (size_t)blockIdx.z * K * N;
    __shared__ float t[32][33];
    int n0 = blockIdx.x * 32, k0 = blockIdx.y * 32;
    int c = threadIdx.x & 31, r0 = threadIdx.x >> 5;
#pragma unroll
    for (int i = 0; i < 4; i++) {
        int r = r0 + i * 8;
        t[r][c] = W[zo + (size_t)(k0 + r) * N + n0 + c];
    }
    __syncthreads();
#pragma unroll
    for (int i = 0; i < 4; i++) {
        int r = r0 + i * 8;
        float v = t[c][r];
        unsigned short h = f2bf(v);
        unsigned short l = f2bf(v - bf2f(h));
        Th[zo + (size_t)(n0 + r) * K + k0 + c] = h;
        Tl[zo + (size_t)(n0 + r) * K + k0 + c] = l;
    }
}

// ---------------- split-bf16 MFMA GEMM: C = A(Mx128) @ B(128xNc) [+bias] [+resid] ----
// B given transposed+split: BTh/BTl [Nc][128]. Tile 64x64, 4 waves (2x2), each wave 2x2
// 16x16 tiles. 3 MFMAs per operand pair (hi*hi + hi*lo + lo*hi).
template <bool BIAS, bool RESID>
__global__ __launch_bounds__(256) void gemm_mfma(
    const float* __restrict__ A, const unsigned short* __restrict__ BTh,
    const unsigned short* __restrict__ BTl, const float* __restrict__ bias,
    const float* __restrict__ resid, float* __restrict__ C, int Nc) {
    __shared__ __align__(16) char Ah[16384], Al[16384], Bh[16384], Bl[16384];
    int tid = threadIdx.x;
    int bN = blockIdx.x * 64, bM = blockIdx.y * 64;
    // stage A (fp32 -> hi/lo bf16), 64 rows x 128 k
#pragma unroll
    for (int i = 0; i < 8; i++) {
        int f = tid + i * 256;
        int row = f >> 5, k0 = (f & 31) * 4;
        int gm = bM + row;
        float4 v = make_float4(0.f, 0.f, 0.f, 0.f);
        if (gm < M_) v = *(const float4*)(A + (size_t)gm * 128 + k0);
        float vv[4] = {v.x, v.y, v.z, v.w};
        unsigned short h[4], l[4];
#pragma unroll
        for (int j = 0; j < 4; j++) { h[j] = f2bf(vv[j]); l[j] = f2bf(vv[j] - bf2f(h[j])); }
        int off = swz256(row, k0 * 2);
        *(short4v*)(Ah + off) = (short4v){(short)h[0], (short)h[1], (short)h[2], (short)h[3]};
        *(short4v*)(Al + off) = (short4v){(short)l[0], (short)l[1], (short)l[2], (short)l[3]};
    }
    // stage B (already bf16 planes), 64 n-rows x 128 k
#pragma unroll
    for (int i = 0; i < 4; i++) {
        int c = tid + i * 256;
        int n = c >> 4, k0 = (c & 15) * 8;
        int off = swz256(n, k0 * 2);
        *(short8*)(Bh + off) = *(const short8*)(BTh + (size_t)(bN + n) * 128 + k0);
        *(short8*)(Bl + off) = *(const short8*)(BTl + (size_t)(bN + n) * 128 + k0);
    }
    __syncthreads();

    int lane = tid & 63, w = tid >> 6;
    int ln = lane & 15, qh = lane >> 4;
    int wr = w >> 1, wc = w & 1;
    f32x4 acc[2][2] = {};
#pragma unroll
    for (int ks = 0; ks < 4; ks++) {
        int kb = ks * 64 + qh * 16;
        short8 a_h[2], a_l[2], b_h[2], b_l[2];
#pragma unroll
        for (int rt = 0; rt < 2; rt++) {
            int r = wr * 32 + rt * 16 + ln;
            a_h[rt] = *(short8*)(Ah + swz256(r, kb));
            a_l[rt] = *(short8*)(Al + swz256(r, kb));
        }
#pragma unroll
        for (int ct = 0; ct < 2; ct++) {
            int n = wc * 32 + ct * 16 + ln;
            b_h[ct] = *(short8*)(Bh + swz256(n, kb));
            b_l[ct] = *(short8*)(Bl + swz256(n, kb));
        }
#pragma unroll
        for (int rt = 0; rt < 2; rt++)
#pragma unroll
            for (int ct = 0; ct < 2; ct++) {
                acc[rt][ct] = __builtin_amdgcn_mfma_f32_16x16x32_bf16(a_h[rt], b_h[ct], acc[rt][ct], 0, 0, 0);
                acc[rt][ct] = __builtin_amdgcn_mfma_f32_16x16x32_bf16(a_h[rt], b_l[ct], acc[rt][ct], 0, 0, 0);
                acc[rt][ct] = __builtin_amdgcn_mfma_f32_16x16x32_bf16(a_l[rt], b_h[ct], acc[rt][ct], 0, 0, 0);
            }
    }
#pragma unroll
    for (int rt = 0; rt < 2; rt++)
#pragma unroll
        for (int ct = 0; ct < 2; ct++) {
            int col = bN + wc * 32 + ct * 16 + ln;
            int row0 = bM + wr * 32 + rt * 16 + qh * 4;
            float bi = BIAS ? bias[col] : 0.0f;
#pragma unroll
            for (int r = 0; r < 4; r++) {
                int row = row0 + r;
                if (row < M_) {
                    float v = acc[rt][ct][r] + bi;
                    if (RESID) v += resid[(size_t)row * Nc + col];
                    C[(size_t)row * Nc + col] = v;
                }
            }
        }
}

// ---------------- masked attention (unchanged this round) ----------------
__global__ void attn_kernel(const float* __restrict__ qkv, const int* __restrict__ mask,
                            float* __restrict__ o) {
    int wid = threadIdx.x >> 6, lid = threadIdx.x & 63;
    int idx = blockIdx.x * 4 + wid;
    if (idx >= B_ * H_ * N_) return;
    int b = idx / (H_ * N_);
    int rem = idx - b * (H_ * N_);
    int h = rem / N_;
    int r = rem - h * N_;

    const float* base = qkv + (size_t)b * N_ * 384;
    const float* qp = base + (size_t)r * 384 + h * HD_;
    float q[16];
#pragma unroll
    for (int d = 0; d < 16; d++) q[d] = qp[d];

    int m0 = mask[b * 4 + 0], m1 = mask[b * 4 + 1], m2 = mask[b * 4 + 2], m3 = mask[b * 4 + 3];

    const float* kb = base + 128 + h * HD_;
    float s[10];
#pragma unroll
    for (int i = 0; i < 10; i++) {
        int c = lid + i * 64;
        float sv = -INFINITY;
        if (c < N_) {
            int mm = (c < 125) ? m0 : (c < 250) ? m1 : (c < 375) ? m2 : m3;
            bool allow = (c >= 500) || (mm != 0);
            if (allow) {
                const float* kp = kb + (size_t)c * 384;
                float acc = 0.0f;
#pragma unroll
                for (int d = 0; d < 16; d++) acc += q[d] * kp[d];
                sv = acc * SCALE_;
            }
        }
        s[i] = sv;
    }
    float mx = s[0];
#pragma unroll
    for (int i = 1; i < 10; i++) mx = fmaxf(mx, s[i]);
    mx = wave_reduce_max(mx);
    float lsum = 0.0f;
#pragma unroll
    for (int i = 0; i < 10; i++) {
        s[i] = expf(s[i] - mx);
        lsum += s[i];
    }
    lsum = wave_reduce_sum(lsum);
    float inv = 1.0f / lsum;

    float acc[16] = {};
    const float* vb = base + 256 + h * HD_;
#pragma unroll
    for (int i = 0; i < 10; i++) {
        int c = lid + i * 64;
        if (c < N_) {
            const float* vp = vb + (size_t)c * 384;
#pragma unroll
            for (int d = 0; d < 16; d++) acc[d] += s[i] * vp[d];
        }
    }
#pragma unroll
    for (int d = 0; d < 16; d++) acc[d] = wave_reduce_sum(acc[d]);
    float outv = 0.0f;
#pragma unroll
    for (int d = 0; d < 16; d++) outv = (lid == d) ? acc[d] : outv;
    if (lid < 16)
        o[(size_t)(b * N_ + r) * D_ + h * HD_ + lid] = outv * inv;
}

// ---------------- out = resid + b2 (pre-init for MLP atomic accumulation) ----------------
__global__ void init_out(const float* __restrict__ resid, const float* __restrict__ b2,
                         float* __restrict__ dest) {
    int idx = blockIdx.x * 256 + threadIdx.x;
    if (idx < M_ * D_) dest[idx] = resid[idx] + b2[idx & 127];
}

// ---------------- fused MLP, split-bf16 MFMA ----------------
// dest += gelu(H2 @ W1 + b1) @ W2 for a 32-row tile; hidden split over grid.y (x8),
// 32 hidden per inner iter. W1h/W1l: [4096][128] (n-major), W2h/W2l: [128][4096] (d-major).
__global__ __launch_bounds__(256) void mlp_mfma(
    const float* __restrict__ H2, const unsigned short* __restrict__ W1h,
    const unsigned short* __restrict__ W1l, const float* __restrict__ b1f,
    const unsigned short* __restrict__ W2h, const unsigned short* __restrict__ W2l,
    float* __restrict__ dest) {
    __shared__ __align__(16) char Hh[8192], Hl[8192], G1h[8192], G1l[8192],
        Ph[2048], Pl[2048], G2h[8192], G2l[8192];
    int tid = threadIdx.x;
    int bM = blockIdx.x * 32;
    int jb = blockIdx.y * 512;
    // stage H tile (32 x 128) fp32 -> hi/lo
#pragma unroll
    for (int i = 0; i < 4; i++) {
        int f = tid + i * 256;
        int row = f >> 5, k0 = (f & 31) * 4;
        int gm = bM + row;
        float4 v = make_float4(0.f, 0.f, 0.f, 0.f);
        if (gm < M_) v = *(const float4*)(H2 + (size_t)gm * 128 + k0);
        float vv[4] = {v.x, v.y, v.z, v.w};
        unsigned short h[4], l[4];
#pragma unroll
        for (int j = 0; j < 4; j++) { h[j] = f2bf(vv[j]); l[j] = f2bf(vv[j] - bf2f(h[j])); }
        int off = swz256(row, k0 * 2);
        *(short4v*)(Hh + off) = (short4v){(short)h[0], (short)h[1], (short)h[2], (short)h[3]};
        *(short4v*)(Hl + off) = (short4v){(short)l[0], (short)l[1], (short)l[2], (short)l[3]};
    }
    int lane = tid & 63, w = tid >> 6;
    int ln = lane & 15, qh = lane >> 4;
    int rt1 = w >> 1, ct1 = w & 1;  // this wave's GEMM1 16x16 tile of P
    f32x4 acc2[2][2] = {};

    for (int it = 0; it < 16; it++) {
        int h0 = jb + it * 32;
        __syncthreads();  // prior-iter LDS readers done
        // stage W1 chunk: rows n=0..31 (global h0+n), k=0..127
#pragma unroll
        for (int i = 0; i < 2; i++) {
            int c = tid + i * 256;
            int n = c >> 4, k0 = (c & 15) * 8;
            int off = swz256(n, k0 * 2);
            *(short8*)(G1h + off) = *(const short8*)(W1h + (size_t)(h0 + n) * 128 + k0);
            *(short8*)(G1l + off) = *(const short8*)(W1l + (size_t)(h0 + n) * 128 + k0);
        }
        // stage W2 chunk: rows d=0..127, k=0..31 (global hidden h0+k)
#pragma unroll
        for (int i = 0; i < 2; i++) {
            int c = tid + i * 256;
            int d = c >> 2, k0 = (c & 3) * 8;
            int off = swz64(d, k0 * 2);
            *(short8*)(G2h + off) = *(const short8*)(W2h + (size_t)d * 4096 + h0 + k0);
            *(short8*)(G2l + off) = *(const short8*)(W2l + (size_t)d * 4096 + h0 + k0);
        }
        __syncthreads();
        // GEMM1: this wave's 16x16 tile of P = H(32x128) @ W1c^T
        f32x4 p = {};
#pragma unroll
        for (int ks = 0; ks < 4; ks++) {
            int kb = ks * 64 + qh * 16;
            short8 ah = *(short8*)(Hh + swz256(rt1 * 16 + ln, kb));
            short8 al = *(short8*)(Hl + swz256(rt1 * 16 + ln, kb));
            short8 bh = *(short8*)(G1h + swz256(ct1 * 16 + ln, kb));
            short8 bl = *(short8*)(G1l + swz256(ct1 * 16 + ln, kb));
            p = __builtin_amdgcn_mfma_f32_16x16x32_bf16(ah, bh, p, 0, 0, 0);
            p = __builtin_amdgcn_mfma_f32_16x16x32_bf16(ah, bl, p, 0, 0, 0);
            p = __builtin_amdgcn_mfma_f32_16x16x32_bf16(al, bh, p, 0, 0, 0);
        }
        // bias + exact gelu, split, write P to LDS
        {
            int hcol = ct1 * 16 + ln;
            float bi = b1f[h0 + hcol];
#pragma unroll
            for (int r = 0; r < 4; r++) {
                float v = p[r] + bi;
                float g = 0.5f * v * (1.0f + erff(v * 0.70710678f));
                unsigned short gh = f2bf(g);
                unsigned short gl = f2bf(g - bf2f(gh));
                int prow = rt1 * 16 + qh * 4 + r;
                int off = swz64(prow, hcol * 2);
                *(short*)(Ph + off) = (short)gh;
                *(short*)(Pl + off) = (short)gl;
            }
        }
        __syncthreads();
        // GEMM2: acc2 += P(32x32) @ W2c(32x128); this wave covers cols w*32..w*32+32
        {
            int kb = qh * 16;  // K=32: single k-step
            short8 pa_h[2], pa_l[2], wb_h[2], wb_l[2];
#pragma unroll
            for (int rt = 0; rt < 2; rt++) {
                pa_h[rt] = *(short8*)(Ph + swz64(rt * 16 + ln, kb));
                pa_l[rt] = *(short8*)(Pl + swz64(rt * 16 + ln, kb));
            }
#pragma unroll
            for (int ct = 0; ct < 2; ct++) {
                int d = w * 32 + ct * 16 + ln;
                wb_h[ct] = *(short8*)(G2h + swz64(d, kb));
                wb_l[ct] = *(short8*)(G2l + swz64(d, kb));
            }
#pragma unroll
            for (int rt = 0; rt < 2; rt++)
#pragma unroll
                for (int ct = 0; ct < 2; ct++) {
                    acc2[rt][ct] = __builtin_amdgcn_mfma_f32_16x16x32_bf16(pa_h[rt], wb_h[ct], acc2[rt][ct], 0, 0, 0);
                    acc2[rt][ct] = __builtin_amdgcn_mfma_f32_16x16x32_bf16(pa_h[rt], wb_l[ct], acc2[rt][ct], 0, 0, 0);
                    acc2[rt][ct] = __builtin_amdgcn_mfma_f32_16x16x32_bf16(pa_l[rt], wb_h[ct], acc2[rt][ct], 0, 0, 0);
                }
        }
    }
#pragma unroll
    for (int rt = 0; rt < 2; rt++)
#pragma unroll
        for (int ct = 0; ct < 2; ct++) {
            int col = w * 32 + ct * 16 + ln;
            int row0 = bM + rt * 16 + qh * 4;
#pragma unroll
            for (int r = 0; r < 4; r++) {
                int row = row0 + r;
                if (row < M_) atomicAdd(&dest[(size_t)row * 128 + col], acc2[rt][ct][r]);
            }
        }
}

extern "C" void kernel_launch(void* const* d_in, const int* in_sizes, int n_in,
                              void* d_out, int out_size, void* d_ws, size_t ws_size,
                              hipStream_t stream) {
    const float* x     = (const float*)d_in[0];
    const int*   mask  = (const int*)d_in[1];
    const float* Wqkv  = (const float*)d_in[2];
    const float* Wproj = (const float*)d_in[3];
    const float* bproj = (const float*)d_in[4];
    const float* g1    = (const float*)d_in[5];
    const float* b1    = (const float*)d_in[6];
    const float* g2    = (const float*)d_in[7];
    const float* b2    = (const float*)d_in[8];
    const float* W1f   = (const float*)d_in[9];
    const float* b1f   = (const float*)d_in[10];
    const float* W2f   = (const float*)d_in[11];
    const float* b2f   = (const float*)d_in[12];
    float* out = (float*)d_out;
    float* ws = (float*)d_ws;

    float* xbuf   = ws;                 // 640000 f
    float* hbuf   = ws + 640000;
    float* qkvbuf = ws + 1280000;       // 1920000 f
    float* obuf   = ws + 3200000;       // 640000 f
    // bf16 hi/lo transposed weight planes
    unsigned short* qh  = (unsigned short*)(ws + 3840000);
    unsigned short* ql  = qh + 3 * 384 * 128;
    unsigned short* phw = ql + 3 * 384 * 128;
    unsigned short* plw = phw + 3 * 128 * 128;
    unsigned short* w1h = plw + 3 * 128 * 128;
    unsigned short* w1l = w1h + 3 * 4096 * 128;
    unsigned short* w2h = w1l + 3 * 4096 * 128;
    unsigned short* w2l = w2h + 3 * 128 * 4096;
    // total ws: 15.36 MB fp32 + 13.37 MB bf16 ≈ 28.7 MB

    // weight prep: transpose + hi/lo split (all layers)
    tsplit<<<dim3(12, 4, 3), 256, 0, stream>>>(Wqkv, qh, ql, 128, 384);
    tsplit<<<dim3(4, 4, 3), 256, 0, stream>>>(Wproj, phw, plw, 128, 128);
    tsplit<<<dim3(128, 4, 3), 256, 0, stream>>>(W1f, w1h, w1l, 128, 4096);
    tsplit<<<dim3(4, 128, 3), 256, 0, stream>>>(W2f, w2h, w2l, 4096, 128);

    for (int l = 0; l < 3; l++) {
        const float* xcur = (l == 0) ? x : xbuf;
        ln_kernel<<<1250, 256, 0, stream>>>(xcur, g1 + l * D_, b1 + l * D_, hbuf);
        gemm_mfma<false, false><<<dim3(6, 79), 256, 0, stream>>>(
            hbuf, qh + (size_t)l * 384 * 128, ql + (size_t)l * 384 * 128,
            nullptr, nullptr, qkvbuf, 384);
        attn_kernel<<<10000, 256, 0, stream>>>(qkvbuf, mask, obuf);
        gemm_mfma<true, true><<<dim3(2, 79), 256, 0, stream>>>(
            obuf, phw + (size_t)l * 128 * 128, plw + (size_t)l * 128 * 128,
            bproj + l * D_, xcur, xbuf, 128);
        ln_kernel<<<1250, 256, 0, stream>>>(xbuf, g2 + l * D_, b2 + l * D_, hbuf);
        float* dest = (l == 2) ? out : xbuf;
        init_out<<<2500, 256, 0, stream>>>(xbuf, b2f + l * D_, dest);
        mlp_mfma<<<dim3(157, 8), 256, 0, stream>>>(
            hbuf, w1h + (size_t)l * 4096 * 128, w1l + (size_t)l * 4096 * 128,
            b1f + (size_t)l * MLP_,
            w2h + (size_t)l * 128 * 4096, w2l + (size_t)l * 128 * 4096, dest);
    }
}

// Round 4
// 567.269 us; speedup vs baseline: 4.1498x; 2.3627x over previous
//
#include <hip/hip_runtime.h>
#include <hip/hip_bf16.h>
#include <math.h>

#define B_ 8
#define N_ 625
#define D_ 128
#define H_ 8
#define HD_ 16
#define MLP_ 4096
#define SCALE_ 0.25f
#define M_ 5000

typedef __attribute__((ext_vector_type(8))) short short8;
typedef __attribute__((ext_vector_type(4))) short short4v;
typedef __attribute__((ext_vector_type(4))) float f32x4;

// ---- bf16 split helpers (RNE via bit trick; inputs finite) ----
__device__ __forceinline__ unsigned short f2bf(float f) {
    unsigned u = __float_as_uint(f);
    unsigned r = (u + 0x7FFFu + ((u >> 16) & 1u)) >> 16;
    return (unsigned short)r;
}
__device__ __forceinline__ float bf2f(unsigned short h) {
    return __uint_as_float(((unsigned)h) << 16);
}

// ---- swizzled LDS byte offsets (row-major bf16 tiles) ----
__device__ __forceinline__ int swz256(int row, int kbyte) {  // 128-k rows (256B)
    return row * 256 + (kbyte ^ ((row & 7) << 4));
}
__device__ __forceinline__ int swz64(int row, int kbyte) {   // 32-k rows (64B)
    return row * 64 + (kbyte ^ ((row & 3) << 4));
}

__device__ __forceinline__ float wave_reduce_sum(float v) {
#pragma unroll
    for (int off = 32; off > 0; off >>= 1) v += __shfl_xor(v, off, 64);
    return v;
}
__device__ __forceinline__ float wave_reduce_max(float v) {
#pragma unroll
    for (int off = 32; off > 0; off >>= 1) v = fmaxf(v, __shfl_xor(v, off, 64));
    return v;
}

// ---------------- LayerNorm: one wave per row ----------------
__global__ void ln_kernel(const float* __restrict__ x, const float* __restrict__ g,
                          const float* __restrict__ b, float* __restrict__ out) {
    int wid = threadIdx.x >> 6;
    int lid = threadIdx.x & 63;
    int row = blockIdx.x * 4 + wid;
    if (row >= M_) return;
    const float* xr = x + (size_t)row * D_;
    float x0 = xr[lid], x1 = xr[lid + 64];
    float mu = wave_reduce_sum(x0 + x1) * (1.0f / D_);
    float d0 = x0 - mu, d1 = x1 - mu;
    float var = wave_reduce_sum(d0 * d0 + d1 * d1) * (1.0f / D_);
    float inv = rsqrtf(var + 1e-5f);
    float* orow = out + (size_t)row * D_;
    orow[lid]      = d0 * inv * g[lid] + b[lid];
    orow[lid + 64] = d1 * inv * g[lid + 64] + b[lid + 64];
}

// ---------------- weight transpose + bf16 hi/lo split ----------------
// W [K][N] fp32 -> Th/Tl [N][K] bf16 (per blockIdx.z layer)
__global__ void tsplit(const float* __restrict__ W, unsigned short* __restrict__ Th,
                       unsigned short* __restrict__ Tl, int K, int N) {
    size_t zo = (size_t)blockIdx.z * K * N;
    __shared__ float t[32][33];
    int n0 = blockIdx.x * 32, k0 = blockIdx.y * 32;
    int c = threadIdx.x & 31, r0 = threadIdx.x >> 5;
#pragma unroll
    for (int i = 0; i < 4; i++) {
        int r = r0 + i * 8;
        t[r][c] = W[zo + (size_t)(k0 + r) * N + n0 + c];
    }
    __syncthreads();
#pragma unroll
    for (int i = 0; i < 4; i++) {
        int r = r0 + i * 8;
        float v = t[c][r];
        unsigned short h = f2bf(v);
        unsigned short l = f2bf(v - bf2f(h));
        Th[zo + (size_t)(n0 + r) * K + k0 + c] = h;
        Tl[zo + (size_t)(n0 + r) * K + k0 + c] = l;
    }
}

// ---------------- split-bf16 MFMA GEMM: C = A(Mx128) @ B(128xNc) [+bias] [+resid] ----
template <bool BIAS, bool RESID>
__global__ __launch_bounds__(256) void gemm_mfma(
    const float* __restrict__ A, const unsigned short* __restrict__ BTh,
    const unsigned short* __restrict__ BTl, const float* __restrict__ bias,
    const float* __restrict__ resid, float* __restrict__ C, int Nc) {
    __shared__ __align__(16) char Ah[16384], Al[16384], Bh[16384], Bl[16384];
    int tid = threadIdx.x;
    int bN = blockIdx.x * 64, bM = blockIdx.y * 64;
#pragma unroll
    for (int i = 0; i < 8; i++) {
        int f = tid + i * 256;
        int row = f >> 5, k0 = (f & 31) * 4;
        int gm = bM + row;
        float4 v = make_float4(0.f, 0.f, 0.f, 0.f);
        if (gm < M_) v = *(const float4*)(A + (size_t)gm * 128 + k0);
        float vv[4] = {v.x, v.y, v.z, v.w};
        unsigned short h[4], l[4];
#pragma unroll
        for (int j = 0; j < 4; j++) { h[j] = f2bf(vv[j]); l[j] = f2bf(vv[j] - bf2f(h[j])); }
        int off = swz256(row, k0 * 2);
        *(short4v*)(Ah + off) = (short4v){(short)h[0], (short)h[1], (short)h[2], (short)h[3]};
        *(short4v*)(Al + off) = (short4v){(short)l[0], (short)l[1], (short)l[2], (short)l[3]};
    }
#pragma unroll
    for (int i = 0; i < 4; i++) {
        int c = tid + i * 256;
        int n = c >> 4, k0 = (c & 15) * 8;
        int off = swz256(n, k0 * 2);
        *(short8*)(Bh + off) = *(const short8*)(BTh + (size_t)(bN + n) * 128 + k0);
        *(short8*)(Bl + off) = *(const short8*)(BTl + (size_t)(bN + n) * 128 + k0);
    }
    __syncthreads();

    int lane = tid & 63, w = tid >> 6;
    int ln = lane & 15, qh = lane >> 4;
    int wr = w >> 1, wc = w & 1;
    f32x4 acc[2][2] = {};
#pragma unroll
    for (int ks = 0; ks < 4; ks++) {
        int kb = ks * 64 + qh * 16;
        short8 a_h[2], a_l[2], b_h[2], b_l[2];
#pragma unroll
        for (int rt = 0; rt < 2; rt++) {
            int r = wr * 32 + rt * 16 + ln;
            a_h[rt] = *(short8*)(Ah + swz256(r, kb));
            a_l[rt] = *(short8*)(Al + swz256(r, kb));
        }
#pragma unroll
        for (int ct = 0; ct < 2; ct++) {
            int n = wc * 32 + ct * 16 + ln;
            b_h[ct] = *(short8*)(Bh + swz256(n, kb));
            b_l[ct] = *(short8*)(Bl + swz256(n, kb));
        }
#pragma unroll
        for (int rt = 0; rt < 2; rt++)
#pragma unroll
            for (int ct = 0; ct < 2; ct++) {
                acc[rt][ct] = __builtin_amdgcn_mfma_f32_16x16x32_bf16(a_h[rt], b_h[ct], acc[rt][ct], 0, 0, 0);
                acc[rt][ct] = __builtin_amdgcn_mfma_f32_16x16x32_bf16(a_h[rt], b_l[ct], acc[rt][ct], 0, 0, 0);
                acc[rt][ct] = __builtin_amdgcn_mfma_f32_16x16x32_bf16(a_l[rt], b_h[ct], acc[rt][ct], 0, 0, 0);
            }
    }
#pragma unroll
    for (int rt = 0; rt < 2; rt++)
#pragma unroll
        for (int ct = 0; ct < 2; ct++) {
            int col = bN + wc * 32 + ct * 16 + ln;
            int row0 = bM + wr * 32 + rt * 16 + qh * 4;
            float bi = BIAS ? bias[col] : 0.0f;
#pragma unroll
            for (int r = 0; r < 4; r++) {
                int row = row0 + r;
                if (row < M_) {
                    float v = acc[rt][ct][r] + bi;
                    if (RESID) v += resid[(size_t)row * Nc + col];
                    C[(size_t)row * Nc + col] = v;
                }
            }
        }
}

// ---------------- LDS-staged masked attention with online softmax ----------------
// grid (79, 64): blockIdx.y = b*8+h, blockIdx.x = 8-row tile. 4 waves, 2 rows/wave.
// KV chunks of 125 rows == modality blocks, so the mask is chunk-uniform:
// masked chunks are skipped entirely (chunk 4 = fusion block always active).
__global__ __launch_bounds__(256) void attn_lds(const float* __restrict__ qkv,
                                                const int* __restrict__ mask,
                                                float* __restrict__ o) {
    __shared__ float Ks[125][20];   // pad 16->20 floats: b128 reads spread over all banks
    __shared__ float Vs[125][20];
    int tid = threadIdx.x;
    int wid = tid >> 6, lid = tid & 63;
    int bh = blockIdx.y;
    int b = bh >> 3, h = bh & 7;
    int row0 = blockIdx.x * 8 + wid * 2;

    const float* base = qkv + (size_t)b * N_ * 384;
    int r0 = min(row0, N_ - 1), r1 = min(row0 + 1, N_ - 1);
    const float* qp0 = base + (size_t)r0 * 384 + h * HD_;
    const float* qp1 = base + (size_t)r1 * 384 + h * HD_;
    float q0[16], q1[16];
#pragma unroll
    for (int d = 0; d < 16; d++) { q0[d] = qp0[d] * SCALE_; q1[d] = qp1[d] * SCALE_; }

    float m = -3.4e38f, l0 = 0.f, l1 = 0.f;
    float acc0[16] = {}, acc1[16] = {};

    for (int ci = 0; ci < 5; ci++) {
        bool active = (ci == 4) || (mask[b * 4 + ci] != 0);  // block-uniform
        if (!active) continue;
        __syncthreads();   // prior chunk's LDS readers done
        const float* kc = base + 128 + h * HD_ + (size_t)ci * 125 * 384;
        const float* vc = base + 256 + h * HD_ + (size_t)ci * 125 * 384;
        for (int e = tid; e < 500; e += 256) {
            int c = e >> 2, d4 = (e & 3) * 4;
            *(float4*)&Ks[c][d4] = *(const float4*)(kc + (size_t)c * 384 + d4);
            *(float4*)&Vs[c][d4] = *(const float4*)(vc + (size_t)c * 384 + d4);
        }
        __syncthreads();

        float s0[2], s1[2];
        float cmax = -3.4e38f;
#pragma unroll
        for (int i = 0; i < 2; i++) {
            int cc = lid + i * 64;
            if (cc < 125) {
                float a0 = 0.f, a1 = 0.f;
#pragma unroll
                for (int d = 0; d < 16; d++) {
                    float kv = Ks[cc][d];
                    a0 += q0[d] * kv;
                    a1 += q1[d] * kv;
                }
                s0[i] = a0; s1[i] = a1;
                cmax = fmaxf(cmax, fmaxf(a0, a1));
            }
        }
        cmax = wave_reduce_max(cmax);
        float mnew = fmaxf(m, cmax);
        if (mnew > m) {               // wave-uniform; skipped when max doesn't grow
            float f = __expf(m - mnew);   // first chunk: exp(-huge)=0, accs are 0
            l0 *= f; l1 *= f;
#pragma unroll
            for (int d = 0; d < 16; d++) { acc0[d] *= f; acc1[d] *= f; }
            m = mnew;
        }
#pragma unroll
        for (int i = 0; i < 2; i++) {
            int cc = lid + i * 64;
            if (cc < 125) {
                float p0 = __expf(s0[i] - m), p1 = __expf(s1[i] - m);
                l0 += p0; l1 += p1;
#pragma unroll
                for (int d = 0; d < 16; d++) {
                    float vv = Vs[cc][d];
                    acc0[d] += p0 * vv;
                    acc1[d] += p1 * vv;
                }
            }
        }
    }

    l0 = wave_reduce_sum(l0); l1 = wave_reduce_sum(l1);
#pragma unroll
    for (int d = 0; d < 16; d++) {
        acc0[d] = wave_reduce_sum(acc0[d]);
        acc1[d] = wave_reduce_sum(acc1[d]);
    }
    float o0 = 0.f, o1 = 0.f;
#pragma unroll
    for (int d = 0; d < 16; d++) {
        o0 = (lid == d) ? acc0[d] : o0;
        o1 = (lid == d) ? acc1[d] : o1;
    }
    if (lid < 16) {
        if (row0 < N_)     o[(size_t)(b * N_ + row0) * D_ + h * HD_ + lid]     = o0 / l0;
        if (row0 + 1 < N_) o[(size_t)(b * N_ + row0 + 1) * D_ + h * HD_ + lid] = o1 / l1;
    }
}

// ---------------- out = resid + b2 (pre-init for MLP atomic accumulation) ----------------
__global__ void init_out(const float* __restrict__ resid, const float* __restrict__ b2,
                         float* __restrict__ dest) {
    int idx = blockIdx.x * 256 + threadIdx.x;
    if (idx < M_ * D_) dest[idx] = resid[idx] + b2[idx & 127];
}

// ---------------- fused MLP, split-bf16 MFMA ----------------
__global__ __launch_bounds__(256) void mlp_mfma(
    const float* __restrict__ H2, const unsigned short* __restrict__ W1h,
    const unsigned short* __restrict__ W1l, const float* __restrict__ b1f,
    const unsigned short* __restrict__ W2h, const unsigned short* __restrict__ W2l,
    float* __restrict__ dest) {
    __shared__ __align__(16) char Hh[8192], Hl[8192], G1h[8192], G1l[8192],
        Ph[2048], Pl[2048], G2h[8192], G2l[8192];
    int tid = threadIdx.x;
    int bM = blockIdx.x * 32;
    int jb = blockIdx.y * 512;
#pragma unroll
    for (int i = 0; i < 4; i++) {
        int f = tid + i * 256;
        int row = f >> 5, k0 = (f & 31) * 4;
        int gm = bM + row;
        float4 v = make_float4(0.f, 0.f, 0.f, 0.f);
        if (gm < M_) v = *(const float4*)(H2 + (size_t)gm * 128 + k0);
        float vv[4] = {v.x, v.y, v.z, v.w};
        unsigned short h[4], l[4];
#pragma unroll
        for (int j = 0; j < 4; j++) { h[j] = f2bf(vv[j]); l[j] = f2bf(vv[j] - bf2f(h[j])); }
        int off = swz256(row, k0 * 2);
        *(short4v*)(Hh + off) = (short4v){(short)h[0], (short)h[1], (short)h[2], (short)h[3]};
        *(short4v*)(Hl + off) = (short4v){(short)l[0], (short)l[1], (short)l[2], (short)l[3]};
    }
    int lane = tid & 63, w = tid >> 6;
    int ln = lane & 15, qh = lane >> 4;
    int rt1 = w >> 1, ct1 = w & 1;
    f32x4 acc2[2][2] = {};

    for (int it = 0; it < 16; it++) {
        int h0 = jb + it * 32;
        __syncthreads();
#pragma unroll
        for (int i = 0; i < 2; i++) {
            int c = tid + i * 256;
            int n = c >> 4, k0 = (c & 15) * 8;
            int off = swz256(n, k0 * 2);
            *(short8*)(G1h + off) = *(const short8*)(W1h + (size_t)(h0 + n) * 128 + k0);
            *(short8*)(G1l + off) = *(const short8*)(W1l + (size_t)(h0 + n) * 128 + k0);
        }
#pragma unroll
        for (int i = 0; i < 2; i++) {
            int c = tid + i * 256;
            int d = c >> 2, k0 = (c & 3) * 8;
            int off = swz64(d, k0 * 2);
            *(short8*)(G2h + off) = *(const short8*)(W2h + (size_t)d * 4096 + h0 + k0);
            *(short8*)(G2l + off) = *(const short8*)(W2l + (size_t)d * 4096 + h0 + k0);
        }
        __syncthreads();
        f32x4 p = {};
#pragma unroll
        for (int ks = 0; ks < 4; ks++) {
            int kb = ks * 64 + qh * 16;
            short8 ah = *(short8*)(Hh + swz256(rt1 * 16 + ln, kb));
            short8 al = *(short8*)(Hl + swz256(rt1 * 16 + ln, kb));
            short8 bh = *(short8*)(G1h + swz256(ct1 * 16 + ln, kb));
            short8 bl = *(short8*)(G1l + swz256(ct1 * 16 + ln, kb));
            p = __builtin_amdgcn_mfma_f32_16x16x32_bf16(ah, bh, p, 0, 0, 0);
            p = __builtin_amdgcn_mfma_f32_16x16x32_bf16(ah, bl, p, 0, 0, 0);
            p = __builtin_amdgcn_mfma_f32_16x16x32_bf16(al, bh, p, 0, 0, 0);
        }
        {
            int hcol = ct1 * 16 + ln;
            float bi = b1f[h0 + hcol];
#pragma unroll
            for (int r = 0; r < 4; r++) {
                float v = p[r] + bi;
                float g = 0.5f * v * (1.0f + erff(v * 0.70710678f));
                unsigned short gh = f2bf(g);
                unsigned short gl = f2bf(g - bf2f(gh));
                int prow = rt1 * 16 + qh * 4 + r;
                int off = swz64(prow, hcol * 2);
                *(short*)(Ph + off) = (short)gh;
                *(short*)(Pl + off) = (short)gl;
            }
        }
        __syncthreads();
        {
            int kb = qh * 16;
            short8 pa_h[2], pa_l[2], wb_h[2], wb_l[2];
#pragma unroll
            for (int rt = 0; rt < 2; rt++) {
                pa_h[rt] = *(short8*)(Ph + swz64(rt * 16 + ln, kb));
                pa_l[rt] = *(short8*)(Pl + swz64(rt * 16 + ln, kb));
            }
#pragma unroll
            for (int ct = 0; ct < 2; ct++) {
                int d = w * 32 + ct * 16 + ln;
                wb_h[ct] = *(short8*)(G2h + swz64(d, kb));
                wb_l[ct] = *(short8*)(G2l + swz64(d, kb));
            }
#pragma unroll
            for (int rt = 0; rt < 2; rt++)
#pragma unroll
                for (int ct = 0; ct < 2; ct++) {
                    acc2[rt][ct] = __builtin_amdgcn_mfma_f32_16x16x32_bf16(pa_h[rt], wb_h[ct], acc2[rt][ct], 0, 0, 0);
                    acc2[rt][ct] = __builtin_amdgcn_mfma_f32_16x16x32_bf16(pa_h[rt], wb_l[ct], acc2[rt][ct], 0, 0, 0);
                    acc2[rt][ct] = __builtin_amdgcn_mfma_f32_16x16x32_bf16(pa_l[rt], wb_h[ct], acc2[rt][ct], 0, 0, 0);
                }
        }
    }
#pragma unroll
    for (int rt = 0; rt < 2; rt++)
#pragma unroll
        for (int ct = 0; ct < 2; ct++) {
            int col = w * 32 + ct * 16 + ln;
            int row0 = bM + rt * 16 + qh * 4;
#pragma unroll
            for (int r = 0; r < 4; r++) {
                int row = row0 + r;
                if (row < M_) atomicAdd(&dest[(size_t)row * 128 + col], acc2[rt][ct][r]);
            }
        }
}

extern "C" void kernel_launch(void* const* d_in, const int* in_sizes, int n_in,
                              void* d_out, int out_size, void* d_ws, size_t ws_size,
                              hipStream_t stream) {
    const float* x     = (const float*)d_in[0];
    const int*   mask  = (const int*)d_in[1];
    const float* Wqkv  = (const float*)d_in[2];
    const float* Wproj = (const float*)d_in[3];
    const float* bproj = (const float*)d_in[4];
    const float* g1    = (const float*)d_in[5];
    const float* b1    = (const float*)d_in[6];
    const float* g2    = (const float*)d_in[7];
    const float* b2    = (const float*)d_in[8];
    const float* W1f   = (const float*)d_in[9];
    const float* b1f   = (const float*)d_in[10];
    const float* W2f   = (const float*)d_in[11];
    const float* b2f   = (const float*)d_in[12];
    float* out = (float*)d_out;
    float* ws = (float*)d_ws;

    float* xbuf   = ws;                 // 640000 f
    float* hbuf   = ws + 640000;
    float* qkvbuf = ws + 1280000;       // 1920000 f
    float* obuf   = ws + 3200000;       // 640000 f
    unsigned short* qh  = (unsigned short*)(ws + 3840000);
    unsigned short* ql  = qh + 3 * 384 * 128;
    unsigned short* phw = ql + 3 * 384 * 128;
    unsigned short* plw = phw + 3 * 128 * 128;
    unsigned short* w1h = plw + 3 * 128 * 128;
    unsigned short* w1l = w1h + 3 * 4096 * 128;
    unsigned short* w2h = w1l + 3 * 4096 * 128;
    unsigned short* w2l = w2h + 3 * 128 * 4096;

    tsplit<<<dim3(12, 4, 3), 256, 0, stream>>>(Wqkv, qh, ql, 128, 384);
    tsplit<<<dim3(4, 4, 3), 256, 0, stream>>>(Wproj, phw, plw, 128, 128);
    tsplit<<<dim3(128, 4, 3), 256, 0, stream>>>(W1f, w1h, w1l, 128, 4096);
    tsplit<<<dim3(4, 128, 3), 256, 0, stream>>>(W2f, w2h, w2l, 4096, 128);

    for (int l = 0; l < 3; l++) {
        const float* xcur = (l == 0) ? x : xbuf;
        ln_kernel<<<1250, 256, 0, stream>>>(xcur, g1 + l * D_, b1 + l * D_, hbuf);
        gemm_mfma<false, false><<<dim3(6, 79), 256, 0, stream>>>(
            hbuf, qh + (size_t)l * 384 * 128, ql + (size_t)l * 384 * 128,
            nullptr, nullptr, qkvbuf, 384);
        attn_lds<<<dim3(79, 64), 256, 0, stream>>>(qkvbuf, mask, obuf);
        gemm_mfma<true, true><<<dim3(2, 79), 256, 0, stream>>>(
            obuf, phw + (size_t)l * 128 * 128, plw + (size_t)l * 128 * 128,
            bproj + l * D_, xcur, xbuf, 128);
        ln_kernel<<<1250, 256, 0, stream>>>(xbuf, g2 + l * D_, b2 + l * D_, hbuf);
        float* dest = (l == 2) ? out : xbuf;
        init_out<<<2500, 256, 0, stream>>>(xbuf, b2f + l * D_, dest);
        mlp_mfma<<<dim3(157, 8), 256, 0, stream>>>(
            hbuf, w1h + (size_t)l * 4096 * 128, w1l + (size_t)l * 4096 * 128,
            b1f + (size_t)l * MLP_,
            w2h + (size_t)l * 128 * 4096, w2l + (size_t)l * 128 * 4096, dest);
    }
}